// Round 19
// baseline (120.968 us; speedup 1.0000x reference)
//
#include <hip/hip_runtime.h>

#define B_   16
#define C_   512
#define HW_  1024
#define G_   32
#define CPG  16
#define EPS  1e-5f
#define CHW  ((size_t)C_ * HW_)        // 524288 elements per batch (c,hw)
#define HW2  ((size_t)HW_ * HW_)       // 1048576 elements per batch (hw,hw)

typedef __attribute__((ext_vector_type(8))) short bf16x8;
typedef __attribute__((ext_vector_type(4))) float f32x4;

__device__ inline unsigned short f2bf(float f) {
    union { float f; unsigned u; } v; v.f = f;
    unsigned r = v.u + 0x7fffu + ((v.u >> 16) & 1u);   // RNE
    return (unsigned short)(r >> 16);
}
__device__ inline float bf2f(unsigned short h) {
    union { unsigned u; float f; } v; v.u = (unsigned)h << 16;
    return v.f;
}

__device__ inline void gload_lds16(const void* g, void* lds) {
    __builtin_amdgcn_global_load_lds(
        (const __attribute__((address_space(1))) void*)g,
        (__attribute__((address_space(3))) void*)lds,
        16, 0, 0);
}

// ---- merged: GroupNorm (blocks 0..511) + weight f2bf (512..1535) + bias ----
__global__ __launch_bounds__(256) void gnprep_kernel(
    const float* __restrict__ x, const float* __restrict__ scale,
    const float* __restrict__ bias, unsigned short* __restrict__ hn_g,
    const float* __restrict__ w0, const float* __restrict__ w1,
    const float* __restrict__ w2, const float* __restrict__ w3,
    unsigned short* __restrict__ o0, unsigned short* __restrict__ o1,
    unsigned short* __restrict__ o2, unsigned short* __restrict__ o3,
    const float* __restrict__ bq, const float* __restrict__ bk,
    float* __restrict__ bqk)
{
    const int id = blockIdx.x;
    if (id >= 1536) {                                     // bias concat
        int t = threadIdx.x;
        bqk[t]       = bq[t];
        bqk[256 + t] = bq[256 + t];
        bqk[512 + t] = bk[t];
        bqk[768 + t] = bk[256 + t];
        return;
    }
    if (id >= 512) {                                      // weight convert
        int wi = id - 512;
        int wsel = wi >> 8;
        int blk  = wi & 255;
        const float* in = (wsel == 0) ? w0 : (wsel == 1) ? w1 : (wsel == 2) ? w2 : w3;
        unsigned short* out = (wsel == 0) ? o0 : (wsel == 1) ? o1 : (wsel == 2) ? o2 : o3;
        int i = (blk * 256 + threadIdx.x) * 4;
        float4 f = *reinterpret_cast<const float4*>(in + i);
        ushort4 o;
        o.x = f2bf(f.x); o.y = f2bf(f.y); o.z = f2bf(f.z); o.w = f2bf(f.w);
        *reinterpret_cast<ushort4*>(out + i) = o;
        return;
    }

    // ---------------- GroupNorm: one HBM read, vectorized both passes ------
    const int bg = id;                                    // b*32 + g
    const int g  = bg & 31;
    const float* xp = x + (size_t)bg * CPG * HW_;         // [16][1024]
    const int N = CPG * HW_;                              // 16384
    const int t = threadIdx.x;

    float s = 0.f, ss = 0.f;
    const float4* xv = reinterpret_cast<const float4*>(xp);
#pragma unroll
    for (int k = 0; k < 16; ++k) {
        float4 v = xv[t + k * 256];
        s  += v.x + v.y + v.z + v.w;
        ss += v.x * v.x + v.y * v.y + v.z * v.z + v.w * v.w;
    }
    for (int off = 32; off; off >>= 1) {
        s  += __shfl_down(s,  off, 64);
        ss += __shfl_down(ss, off, 64);
    }
    __shared__ float red0[4], red1[4];
    int lane = t & 63, wid = t >> 6;
    if (lane == 0) { red0[wid] = s; red1[wid] = ss; }
    __syncthreads();
    __shared__ float smu, sinv;
    if (t == 0) {
        float S  = red0[0] + red0[1] + red0[2] + red0[3];
        float SS = red1[0] + red1[1] + red1[2] + red1[3];
        float mu = S / (float)N;
        float var = SS / (float)N - mu * mu;
        smu = mu; sinv = rsqrtf(var + EPS);
    }
    __syncthreads();
    const float mu = smu, inv = sinv;

    float scl[CPG], bia[CPG];
#pragma unroll
    for (int cc = 0; cc < CPG; ++cc) {
        float sc = scale[g * CPG + cc];
        scl[cc] = sc * inv;
        bia[cc] = bias[g * CPG + cc] - mu * sc * inv;
    }

    float4 vals[CPG];
#pragma unroll
    for (int cc = 0; cc < CPG; ++cc)
        vals[cc] = xv[cc * 256 + t];
    unsigned short* dst = hn_g + (size_t)bg * 16384 + (size_t)t * 64;  // 4 rows x 16
    __align__(16) unsigned short y[4][CPG];
#pragma unroll
    for (int cc = 0; cc < CPG; ++cc) {
        y[0][cc] = f2bf(vals[cc].x * scl[cc] + bia[cc]);
        y[1][cc] = f2bf(vals[cc].y * scl[cc] + bia[cc]);
        y[2][cc] = f2bf(vals[cc].z * scl[cc] + bia[cc]);
        y[3][cc] = f2bf(vals[cc].w * scl[cc] + bia[cc]);
    }
#pragma unroll
    for (int r = 0; r < 4; ++r) {
        *reinterpret_cast<uint4*>(dst + r * 16)     = *reinterpret_cast<uint4*>(&y[r][0]);
        *reinterpret_cast<uint4*>(dst + r * 16 + 8) = *reinterpret_cast<uint4*>(&y[r][8]);
    }
}

// ====== 128x128 NT bf16 MFMA GEMM body (r12-verified 4-phase schedule) ======
// C[m][n] = alpha * sum_k A[.] * B[.]  (+bias) (+res)
// GA/GB: 1 = group-blocked hn_g[b][g][i][16] operand.
// BIASMODE: 0 none, 1 per-row bias[m], 2 per-col bias[n].
// EEXP: apply __expf to the scaled accumulator before store (max-free softmax
//       numerator — scores here have |s| <~ 2, exp is overflow-safe).
// SCALECOL: multiply the matmul term by invl[bz*1024 + col] (deferred 1/l).
template<int OUTF32, int BIASMODE, int HASRES, int GA, int GB, int EEXP, int SCALECOL>
__device__ __forceinline__ void gemm_body(
    short* lds, int bx, int by, int bz,
    const short* __restrict__ A, size_t sA, int ldA,
    const short* __restrict__ Bm, size_t sB, int ldB,
    void* __restrict__ Cm, size_t sC, int ldC,
    const float* __restrict__ bias,
    const float* __restrict__ res, size_t sR,
    int K, float alpha, const float* __restrict__ invl)
{
    const short* Ab = A  + (size_t)bz * sA;
    const short* Bb = Bm + (size_t)bz * sB;
    const int m0 = by * 128;
    const int n0 = bx * 128;

    const int t = threadIdx.x;
    const int wv = t >> 6, lane = t & 63;
    const int wm = wv >> 1, wn = wv & 1;
    const int fr = lane & 15;
    const int cb = (lane >> 4) * 16;

    // staging source offsets (pre-swizzled) for the two 4KB halves of a slot
    size_t srcA0, srcA1, srcB0, srcB1;
    {
        int p0 = t * 16;
        int a0 = p0 ^ (((p0 >> 7) & 3) << 4);
        int p1 = 4096 + t * 16;
        int a1 = p1 ^ (((p1 >> 7) & 3) << 4);
        int r0 = a0 >> 6, cs0 = (a0 & 63) >> 1;   // row 0..127, k-shorts 0..31
        int r1 = a1 >> 6, cs1 = (a1 & 63) >> 1;
        if (GA) {
            int mA0 = m0 + r0, mA1 = m0 + r1;
            srcA0 = (size_t)(mA0 >> 10) * 524288 + (size_t)(cs0 >> 4) * 16384
                  + (size_t)(mA0 & 1023) * 16 + (cs0 & 15);
            srcA1 = (size_t)(mA1 >> 10) * 524288 + (size_t)(cs1 >> 4) * 16384
                  + (size_t)(mA1 & 1023) * 16 + (cs1 & 15);
        } else {
            srcA0 = (size_t)(m0 + r0) * ldA + cs0;
            srcA1 = (size_t)(m0 + r1) * ldA + cs1;
        }
        if (GB) {
            int nB0 = n0 + r0, nB1 = n0 + r1;
            srcB0 = (size_t)(nB0 >> 10) * 524288 + (size_t)(cs0 >> 4) * 16384
                  + (size_t)(nB0 & 1023) * 16 + (cs0 & 15);
            srcB1 = (size_t)(nB1 >> 10) * 524288 + (size_t)(cs1 >> 4) * 16384
                  + (size_t)(nB1 & 1023) * 16 + (cs1 & 15);
        } else {
            srcB0 = (size_t)(n0 + r0) * ldB + cs0;
            srcB1 = (size_t)(n0 + r1) * ldB + cs1;
        }
    }
    auto stageA = [&](int par, int kh, int kt_src) {
        const size_t k0 = (size_t)(kt_src * 64 + kh * 32) * (GA ? 1024 : 1);
        const short* s = Ab + k0;
        short* d = &lds[(par * 2 + kh) * 4096 + t * 8];
        gload_lds16(s + srcA0, d);
        gload_lds16(s + srcA1, d + 2048);
    };
    auto stageB = [&](int par, int kh, int kt_src) {
        const size_t k0 = (size_t)(kt_src * 64 + kh * 32) * (GB ? 1024 : 1);
        const short* s = Bb + k0;
        short* d = &lds[16384 + (par * 2 + kh) * 4096 + t * 8];
        gload_lds16(s + srcB0, d);
        gload_lds16(s + srcB1, d + 2048);
    };

    // fragment ds_read byte offsets within slot (swizzled), K-invariant
    int aoffs[4], boffs[4];
#pragma unroll
    for (int fi = 0; fi < 4; ++fi) {
        int row = wm * 64 + fi * 16 + fr;
        int off = row * 64 + cb;
        aoffs[fi] = off ^ (((off >> 7) & 3) << 4);
    }
#pragma unroll
    for (int fj = 0; fj < 4; ++fj) {
        int row = wn * 64 + fj * 16 + fr;
        int off = row * 64 + cb;
        boffs[fj] = off ^ (((off >> 7) & 3) << 4);
    }

    f32x4 acc[4][4];
#pragma unroll
    for (int i = 0; i < 4; ++i)
#pragma unroll
        for (int j = 0; j < 4; ++j) acc[i][j] = (f32x4){0.f, 0.f, 0.f, 0.f};

    const int NT = K >> 6;
    const char* L = (const char*)lds;

    // prologue: 12 per-thread loads
    stageA(0, 0, 0); stageB(0, 0, 0);
    stageA(0, 1, 0); stageB(0, 1, 0);
    stageA(1, 0, 1); stageB(1, 0, 1);

    for (int kt = 0; kt < NT; ++kt) {
        const int par = kt & 1;
        const int AB0 = (par * 2) * 8192;         // byte bases
        const int AB1 = AB0 + 8192;
        const int BB0 = 32768 + (par * 2) * 8192;
        const int BB1 = BB0 + 8192;

        bf16x8 af0, af1, af2, af3, bf0, bf1;

        // ---------- phase 0: ks=0, fj 0-1 ----------
        if (kt == NT - 1) asm volatile("s_waitcnt vmcnt(4)\n\ts_barrier" ::: "memory");
        else              asm volatile("s_waitcnt vmcnt(8)\n\ts_barrier" ::: "memory");
        af0 = *(const bf16x8*)(L + AB0 + aoffs[0]);
        af1 = *(const bf16x8*)(L + AB0 + aoffs[1]);
        af2 = *(const bf16x8*)(L + AB0 + aoffs[2]);
        af3 = *(const bf16x8*)(L + AB0 + aoffs[3]);
        bf0 = *(const bf16x8*)(L + BB0 + boffs[0]);
        bf1 = *(const bf16x8*)(L + BB0 + boffs[1]);
        if (kt + 1 < NT) stageA(par ^ 1, 1, kt + 1);
        __builtin_amdgcn_s_setprio(1);
        acc[0][0] = __builtin_amdgcn_mfma_f32_16x16x32_bf16(af0, bf0, acc[0][0], 0, 0, 0);
        acc[1][0] = __builtin_amdgcn_mfma_f32_16x16x32_bf16(af1, bf0, acc[1][0], 0, 0, 0);
        acc[2][0] = __builtin_amdgcn_mfma_f32_16x16x32_bf16(af2, bf0, acc[2][0], 0, 0, 0);
        acc[3][0] = __builtin_amdgcn_mfma_f32_16x16x32_bf16(af3, bf0, acc[3][0], 0, 0, 0);
        acc[0][1] = __builtin_amdgcn_mfma_f32_16x16x32_bf16(af0, bf1, acc[0][1], 0, 0, 0);
        acc[1][1] = __builtin_amdgcn_mfma_f32_16x16x32_bf16(af1, bf1, acc[1][1], 0, 0, 0);
        acc[2][1] = __builtin_amdgcn_mfma_f32_16x16x32_bf16(af2, bf1, acc[2][1], 0, 0, 0);
        acc[3][1] = __builtin_amdgcn_mfma_f32_16x16x32_bf16(af3, bf1, acc[3][1], 0, 0, 0);
        __builtin_amdgcn_s_setprio(0);
        asm volatile("s_waitcnt lgkmcnt(0)\n\ts_barrier" ::: "memory");

        // ---------- phase 1: ks=0, fj 2-3 ----------
        bf0 = *(const bf16x8*)(L + BB0 + boffs[2]);
        bf1 = *(const bf16x8*)(L + BB0 + boffs[3]);
        if (kt + 1 < NT) stageB(par ^ 1, 1, kt + 1);
        __builtin_amdgcn_s_setprio(1);
        acc[0][2] = __builtin_amdgcn_mfma_f32_16x16x32_bf16(af0, bf0, acc[0][2], 0, 0, 0);
        acc[1][2] = __builtin_amdgcn_mfma_f32_16x16x32_bf16(af1, bf0, acc[1][2], 0, 0, 0);
        acc[2][2] = __builtin_amdgcn_mfma_f32_16x16x32_bf16(af2, bf0, acc[2][2], 0, 0, 0);
        acc[3][2] = __builtin_amdgcn_mfma_f32_16x16x32_bf16(af3, bf0, acc[3][2], 0, 0, 0);
        acc[0][3] = __builtin_amdgcn_mfma_f32_16x16x32_bf16(af0, bf1, acc[0][3], 0, 0, 0);
        acc[1][3] = __builtin_amdgcn_mfma_f32_16x16x32_bf16(af1, bf1, acc[1][3], 0, 0, 0);
        acc[2][3] = __builtin_amdgcn_mfma_f32_16x16x32_bf16(af2, bf1, acc[2][3], 0, 0, 0);
        acc[3][3] = __builtin_amdgcn_mfma_f32_16x16x32_bf16(af3, bf1, acc[3][3], 0, 0, 0);
        __builtin_amdgcn_s_setprio(0);
        asm volatile("s_waitcnt lgkmcnt(0)\n\ts_barrier" ::: "memory");

        // ---------- phase 2: ks=1, fj 0-1 ----------
        if (kt == NT - 1) asm volatile("s_waitcnt vmcnt(0)\n\ts_barrier" ::: "memory");
        else              asm volatile("s_waitcnt vmcnt(8)\n\ts_barrier" ::: "memory");
        af0 = *(const bf16x8*)(L + AB1 + aoffs[0]);
        af1 = *(const bf16x8*)(L + AB1 + aoffs[1]);
        af2 = *(const bf16x8*)(L + AB1 + aoffs[2]);
        af3 = *(const bf16x8*)(L + AB1 + aoffs[3]);
        bf0 = *(const bf16x8*)(L + BB1 + boffs[0]);
        bf1 = *(const bf16x8*)(L + BB1 + boffs[1]);
        if (kt + 2 < NT) stageA(par, 0, kt + 2);
        __builtin_amdgcn_s_setprio(1);
        acc[0][0] = __builtin_amdgcn_mfma_f32_16x16x32_bf16(af0, bf0, acc[0][0], 0, 0, 0);
        acc[1][0] = __builtin_amdgcn_mfma_f32_16x16x32_bf16(af1, bf0, acc[1][0], 0, 0, 0);
        acc[2][0] = __builtin_amdgcn_mfma_f32_16x16x32_bf16(af2, bf0, acc[2][0], 0, 0, 0);
        acc[3][0] = __builtin_amdgcn_mfma_f32_16x16x32_bf16(af3, bf0, acc[3][0], 0, 0, 0);
        acc[0][1] = __builtin_amdgcn_mfma_f32_16x16x32_bf16(af0, bf1, acc[0][1], 0, 0, 0);
        acc[1][1] = __builtin_amdgcn_mfma_f32_16x16x32_bf16(af1, bf1, acc[1][1], 0, 0, 0);
        acc[2][1] = __builtin_amdgcn_mfma_f32_16x16x32_bf16(af2, bf1, acc[2][1], 0, 0, 0);
        acc[3][1] = __builtin_amdgcn_mfma_f32_16x16x32_bf16(af3, bf1, acc[3][1], 0, 0, 0);
        __builtin_amdgcn_s_setprio(0);
        asm volatile("s_waitcnt lgkmcnt(0)\n\ts_barrier" ::: "memory");

        // ---------- phase 3: ks=1, fj 2-3 ----------
        bf0 = *(const bf16x8*)(L + BB1 + boffs[2]);
        bf1 = *(const bf16x8*)(L + BB1 + boffs[3]);
        if (kt + 2 < NT) stageB(par, 0, kt + 2);
        __builtin_amdgcn_s_setprio(1);
        acc[0][2] = __builtin_amdgcn_mfma_f32_16x16x32_bf16(af0, bf0, acc[0][2], 0, 0, 0);
        acc[1][2] = __builtin_amdgcn_mfma_f32_16x16x32_bf16(af1, bf0, acc[1][2], 0, 0, 0);
        acc[2][2] = __builtin_amdgcn_mfma_f32_16x16x32_bf16(af2, bf0, acc[2][2], 0, 0, 0);
        acc[3][2] = __builtin_amdgcn_mfma_f32_16x16x32_bf16(af3, bf0, acc[3][2], 0, 0, 0);
        acc[0][3] = __builtin_amdgcn_mfma_f32_16x16x32_bf16(af0, bf1, acc[0][3], 0, 0, 0);
        acc[1][3] = __builtin_amdgcn_mfma_f32_16x16x32_bf16(af1, bf1, acc[1][3], 0, 0, 0);
        acc[2][3] = __builtin_amdgcn_mfma_f32_16x16x32_bf16(af2, bf1, acc[2][3], 0, 0, 0);
        acc[3][3] = __builtin_amdgcn_mfma_f32_16x16x32_bf16(af3, bf1, acc[3][3], 0, 0, 0);
        __builtin_amdgcn_s_setprio(0);
        asm volatile("s_waitcnt lgkmcnt(0)\n\ts_barrier" ::: "memory");
    }

    // C/D layout: col = lane&15, row = (lane>>4)*4 + reg  [m89-verified]
    const int rq = (lane >> 4) * 4;
    float il[4];
    if (SCALECOL) {
#pragma unroll
        for (int fj = 0; fj < 4; ++fj)
            il[fj] = invl[bz * 1024 + n0 + wn * 64 + fj * 16 + fr];
    }
#pragma unroll
    for (int fi = 0; fi < 4; ++fi) {
#pragma unroll
        for (int rg = 0; rg < 4; ++rg) {
            int row = m0 + wm * 64 + fi * 16 + rq + rg;
            float bm = (BIASMODE == 1) ? bias[row] : 0.f;
#pragma unroll
            for (int fj = 0; fj < 4; ++fj) {
                int col = n0 + wn * 64 + fj * 16 + fr;
                float base = acc[fi][fj][rg] * alpha;
                if (SCALECOL) base *= il[fj];
                float vv = base + bm;
                if (BIASMODE == 2) vv += bias[col];
                if (EEXP) vv = __expf(vv);
                size_t off = (size_t)row * ldC + col;
                if (HASRES) vv += res[(size_t)bz * sR + off];
                if (OUTF32) ((float*)Cm)[(size_t)bz * sC + off] = vv;
                else ((unsigned short*)Cm)[(size_t)bz * sC + off] = f2bf(vv);
            }
        }
    }
}

// wrapper: flattened grid, XCD-aware bijective swizzle, (lx,ly) decode
template<int OUTF32, int BIASMODE, int HASRES, int GA, int GB, int EEXP, int SCALECOL>
__global__ __launch_bounds__(256) void gemm_4w(
    const short* __restrict__ A, size_t sA, int ldA,
    const short* __restrict__ Bm, size_t sB, int ldB,
    void* __restrict__ Cm, size_t sC, int ldC,
    const float* __restrict__ bias,
    const float* __restrict__ res, size_t sR,
    int K, float alpha, int lx, int ly, const float* invl)
{
    __shared__ __align__(16) short lds[32768];    // 64 KB
    const int h = blockIdx.x;
    const int w = (h & 7) * ((int)gridDim.x >> 3) + (h >> 3);   // XCD swizzle
    const int bx = w & ((1 << lx) - 1);
    const int by = (w >> lx) & ((1 << ly) - 1);
    const int bz = w >> (lx + ly);
    gemm_body<OUTF32, BIASMODE, HASRES, GA, GB, EEXP, SCALECOL>(
        lds, bx, by, bz, A, sA, ldA, Bm, sB, ldB, Cm, sC, ldC,
        bias, res, sR, K, alpha, invl);
}

// merged QK-proj + V-proj: 1536 blocks (w<1024: QK, else V), XCD-swizzled
__global__ __launch_bounds__(256) void qkv_kernel(
    const short* __restrict__ hn_g, const short* __restrict__ wsq,
    const float* __restrict__ bqk, short* __restrict__ qk_t,
    const short* __restrict__ wsv, const float* __restrict__ bv,
    short* __restrict__ v)
{
    __shared__ __align__(16) short lds[32768];    // 64 KB
    const int h = blockIdx.x;
    const int w = (h & 7) * 192 + (h >> 3);       // 1536/8 = 192
    if (w < 1024) {
        gemm_body<0, 2, 0, 1, 0, 0, 0>(lds, w & 7, w >> 3, 0,
            hn_g, 0, 0, wsq, 0, C_, qk_t, 0, HW_, bqk, nullptr, 0, C_, 1.0f, nullptr);
    } else {
        const int u = w - 1024;
        gemm_body<0, 1, 0, 0, 1, 0, 0>(lds, u & 7, (u >> 3) & 3, u >> 5,
            wsv, 0, C_, hn_g, CHW, 0, v, CHW, HW_, bv, nullptr, 0, C_, 1.0f, nullptr);
    }
}

// ------ merged PV GEMM (blocks 0..511) + rowsum backfill (512..4607) --------
// PV and rowsum both depend only on the exp'd attn; rowsum blocks (no-barrier,
// one wave per row) backfill CUs as PV rounds retire.
__global__ __launch_bounds__(256) void pv_kernel(
    const short* __restrict__ attn, const short* __restrict__ v,
    short* __restrict__ ao_t, float* __restrict__ invl)
{
    __shared__ __align__(16) short lds[32768];    // 64 KB
    const int h = blockIdx.x;
    if (h < 512) {
        // ao_t[i][c] = sum_j attn[i][j] * v[c][j]  (unnormalized); grid (4,8,16)
        const int w = (h & 7) * 64 + (h >> 3);
        gemm_body<0, 0, 0, 0, 0, 0, 0>(lds, w & 3, (w >> 2) & 7, w >> 5,
            attn, HW2, HW_, v, CHW, HW_, ao_t, CHW, C_,
            nullptr, nullptr, 0, HW_, 1.0f, nullptr);
    } else {
        // invl[row] = 1 / sum_j attn[row][j]; XCD-aligned rows
        const int u = h - 512;                    // 0..4095
        const int g = (u & 7) * 512 + (u >> 3);   // row group (4 rows)
        const int wv = threadIdx.x >> 6, lane = threadIdx.x & 63;
        const unsigned short* p = (const unsigned short*)attn + ((size_t)g * 4 + wv) * HW_;
        float sum = 0.f;
#pragma unroll
        for (int k = 0; k < 4; ++k) {
            ushort4 raw = reinterpret_cast<const ushort4*>(p)[lane + k * 64];
            sum += bf2f(raw.x) + bf2f(raw.y) + bf2f(raw.z) + bf2f(raw.w);
        }
        for (int off = 32; off; off >>= 1) sum += __shfl_xor(sum, off, 64);
        if (lane == 0) invl[g * 4 + wv] = 1.0f / sum;
    }
}

extern "C" void kernel_launch(void* const* d_in, const int* in_sizes, int n_in,
                              void* d_out, int out_size, void* d_ws, size_t ws_size,
                              hipStream_t stream)
{
    const float* x        = (const float*)d_in[0];
    // d_in[1] = temb : unused by the reference
    const float* gn_scale = (const float*)d_in[2];
    const float* gn_bias  = (const float*)d_in[3];
    const float* wq = (const float*)d_in[4];
    const float* bq = (const float*)d_in[5];
    const float* wk = (const float*)d_in[6];
    const float* bk = (const float*)d_in[7];
    const float* wv = (const float*)d_in[8];
    const float* bv = (const float*)d_in[9];
    const float* wo = (const float*)d_in[10];
    const float* bo = (const float*)d_in[11];
    float* out = (float*)d_out;

    // workspace layout (bf16 elements)
    short* ws = (short*)d_ws;
    const size_t E = (size_t)B_ * C_ * HW_;        // 8388608
    short* hn_g = ws;                              // [b][g][i][16]      E
    short* qk_t = hn_g + E;                        // [b*i][q||k]        2E
    short* v    = qk_t + 2 * E;                    // [b][c][j]          E
    short* ao_t = v + E;                           // [b][i][c] raw      E
    short* attn = ao_t + E;                        // [b][i][j] exp'd    2E
    short* wsq  = attn + 2 * E;                    // wq||wk||wv||wo bf16
    short* wsk  = wsq + (size_t)C_ * C_;
    short* wsv  = wsk + (size_t)C_ * C_;
    short* wso  = wsv + (size_t)C_ * C_;
    float* bqk  = (float*)(wso + (size_t)C_ * C_); // 1024 f32
    float* invl = bqk + 1024;                      // 16384 f32

    const float inv_sqrt_c = 0.044194173824159216f;   // 512^-0.5

    // merged GN + weight convert + bias concat (GN blocks first: critical path)
    gnprep_kernel<<<dim3(1537), 256, 0, stream>>>(
        x, gn_scale, gn_bias, (unsigned short*)hn_g,
        wq, wk, wv, wo,
        (unsigned short*)wsq, (unsigned short*)wsk,
        (unsigned short*)wsv, (unsigned short*)wso,
        bq, bk, bqk);

    // merged QK-projection (1024 blocks) + V-projection (512 blocks)
    qkv_kernel<<<dim3(1536), 256, 0, stream>>>(
        hn_g, wsq, bqk, qk_t, wsv, bv, v);

    // attn[i][j] = exp((sum_c q[i][c]*k[j][c]) * C^-0.5)  (max-free numerator)
    gemm_4w<0, 0, 0, 0, 0, 1, 0><<<dim3(1024), 256, 0, stream>>>(
        qk_t, HW2, HW_, qk_t + C_, HW2, HW_, attn, HW2, HW_,
        nullptr, nullptr, 0, C_, inv_sqrt_c, 3, 3, nullptr);  // grid (8,8,16)

    // merged PV (unnormalized) + rowsum backfill
    pv_kernel<<<dim3(4608), 256, 0, stream>>>(attn, v, ao_t, invl);

    // out[c][i] = x + (sum_k wo[c][k] * ao_t[i][k]) * invl[i] + bo[c]
    gemm_4w<1, 1, 1, 0, 0, 0, 1><<<dim3(512), 256, 0, stream>>>(
        wso, 0, C_, ao_t, CHW, C_, out, CHW, HW_, bo, x, CHW, C_,
        1.0f, 3, 2, invl);                                    // grid (8,4,16)
}